// Round 4
// baseline (372.913 us; speedup 1.0000x reference)
//
#include <hip/hip_runtime.h>
#include <math.h>

#define E_DIM 128
#define R_DIM 128
#define N_REL 64
#define REG_LAMBDA 1e-5f
#define G 8          // samples per chunk (fixed-size, same relation)

// ---------------- Kernel A: counting-sort by relation + chunk descriptors ----
// 1 block, 1024 threads. hist -> wave-wide prefix (wave 0) -> scatter ->
// emit descriptors (start, rel, len) of exactly-G sorted samples per chunk.
__global__ void __launch_bounds__(1024)
kge_sort_kernel(const int* __restrict__ r_idx, int M,
                int* __restrict__ sorted, int2* __restrict__ desc,
                int* __restrict__ nchunks_out)
{
    const int t = threadIdx.x;
    __shared__ int hist[N_REL], base[N_REL], cursor[N_REL];
    __shared__ int s_total;

    if (t < N_REL) { hist[t] = 0; cursor[t] = 0; }
    __syncthreads();

    for (int m = t; m < M; m += 1024) atomicAdd(&hist[r_idx[m]], 1);
    __syncthreads();

    if (t < N_REL) {  // wave 0, lanes 0..63
        const int c = hist[t];
        int x = c;
#pragma unroll
        for (int off = 1; off < 64; off <<= 1) {
            int y = __shfl_up(x, off);
            if (t >= off) x += y;
        }
        base[t] = x - c;                    // exclusive prefix of counts
        const int nch = (c + G - 1) / G;
        int z = nch;
#pragma unroll
        for (int off = 1; off < 64; off <<= 1) {
            int y = __shfl_up(z, off);
            if (t >= off) z += y;
        }
        const int cb = z - nch;             // chunk base for this relation
        if (t == N_REL - 1) s_total = z;
        for (int j = 0; j < nch; ++j) {
            int len = c - j * G; if (len > G) len = G;
            desc[cb + j] = make_int2((x - c) + j * G, (t << 16) | len);
        }
    }
    __syncthreads();

    for (int m = t; m < M; m += 1024) {
        int r = r_idx[m];
        int p = base[r] + atomicAdd(&cursor[r], 1);
        sorted[p] = m;
    }
    if (t == 0) nchunks_out[0] = s_total;
}

// ---------------- Kernel B: one fixed chunk of G same-relation samples ------
// 256 threads = 4 waves. Wave q owns e-quarter [32q,32q+32); lane u=t&63 owns
// cols 2u,2u+1. Each W float2 (regs, L2) feeds 3*G*2=48 FMAs; each LDS b128
// broadcast feeds 16 FMAs. Cross-wave partials via LDS in 2 rounds of 4.
// Per-sample arithmetic byte-identical to the v4 kernel (absmax 0.0).
__global__ void __launch_bounds__(256, 4)
kge_chunk_kernel(const int* __restrict__ sorted, const int2* __restrict__ desc,
                 const int* __restrict__ nchunks_ptr,
                 const int* __restrict__ h_idx, const int* __restrict__ pt_idx,
                 const int* __restrict__ nt_idx,
                 const float* __restrict__ ent,   // (N_ENT, 128)
                 const float* __restrict__ rel,   // (64, 128)
                 const float* __restrict__ W,     // (64, 128, 128)
                 float* __restrict__ per_sample)  // (M,)
{
    const int bid = blockIdx.x;
    if (bid >= nchunks_ptr[0]) return;
    const int2 d     = desc[bid];
    const int start  = d.x;
    const int rel_id = d.y >> 16;
    const int len    = d.y & 0xffff;   // 1..G

    const int t  = threadIdx.x;        // 0..255
    const int q  = t >> 6;             // wave -> e-quarter
    const int u  = t & 63;
    const int cb = u << 1;             // first owned column

    __shared__ __align__(16) float sh[G][E_DIM];
    __shared__ __align__(16) float sp[G][E_DIM];
    __shared__ __align__(16) float sn[G][E_DIM];
    __shared__ __align__(16) float epi[4][3][4][R_DIM];  // [g][vec][waveq][col]
    __shared__ float wpart[3][G][2];
    __shared__ int s_ids[G];

    if (t < G) s_ids[t] = sorted[start + min(t, len - 1)];  // pad: clamp
    __syncthreads();

    const int elem = t & 127;
    const int half = t >> 7;
    for (int g = half; g < G; g += 2) {
        int m = s_ids[g];
        sh[g][elem] = ent[(size_t)h_idx[m]  * E_DIM + elem];
        sp[g][elem] = ent[(size_t)pt_idx[m] * E_DIM + elem];
        sn[g][elem] = ent[(size_t)nt_idx[m] * E_DIM + elem];
    }
    __syncthreads();

    const float* __restrict__ Wq =
        W + (size_t)rel_id * (E_DIM * R_DIM) + (size_t)(q << 5) * R_DIM + cb;
    const float re = (t < E_DIM) ? rel[(size_t)rel_id * R_DIM + t] : 0.f;

    float aH[G][2], aP[G][2], aN[G][2];
#pragma unroll
    for (int g = 0; g < G; ++g) {
        aH[g][0] = 0.f; aH[g][1] = 0.f;
        aP[g][0] = 0.f; aP[g][1] = 0.f;
        aN[g][0] = 0.f; aN[g][1] = 0.f;
    }

    const int eBase = q << 5;
#pragma unroll 2
    for (int es = 0; es < 8; ++es) {
        const int e0 = eBase + (es << 2);
        const float2 w0 = *(const float2*)(Wq + (size_t)((es << 2) + 0) * R_DIM);
        const float2 w1 = *(const float2*)(Wq + (size_t)((es << 2) + 1) * R_DIM);
        const float2 w2 = *(const float2*)(Wq + (size_t)((es << 2) + 2) * R_DIM);
        const float2 w3 = *(const float2*)(Wq + (size_t)((es << 2) + 3) * R_DIM);
#pragma unroll
        for (int g = 0; g < G; ++g) {
            const float4 h4 = *(const float4*)&sh[g][e0];
            const float4 p4 = *(const float4*)&sp[g][e0];
            const float4 n4 = *(const float4*)&sn[g][e0];
            aH[g][0] = fmaf(h4.x, w0.x, aH[g][0]);
            aH[g][0] = fmaf(h4.y, w1.x, aH[g][0]);
            aH[g][0] = fmaf(h4.z, w2.x, aH[g][0]);
            aH[g][0] = fmaf(h4.w, w3.x, aH[g][0]);
            aH[g][1] = fmaf(h4.x, w0.y, aH[g][1]);
            aH[g][1] = fmaf(h4.y, w1.y, aH[g][1]);
            aH[g][1] = fmaf(h4.z, w2.y, aH[g][1]);
            aH[g][1] = fmaf(h4.w, w3.y, aH[g][1]);
            aP[g][0] = fmaf(p4.x, w0.x, aP[g][0]);
            aP[g][0] = fmaf(p4.y, w1.x, aP[g][0]);
            aP[g][0] = fmaf(p4.z, w2.x, aP[g][0]);
            aP[g][0] = fmaf(p4.w, w3.x, aP[g][0]);
            aP[g][1] = fmaf(p4.x, w0.y, aP[g][1]);
            aP[g][1] = fmaf(p4.y, w1.y, aP[g][1]);
            aP[g][1] = fmaf(p4.z, w2.y, aP[g][1]);
            aP[g][1] = fmaf(p4.w, w3.y, aP[g][1]);
            aN[g][0] = fmaf(n4.x, w0.x, aN[g][0]);
            aN[g][0] = fmaf(n4.y, w1.x, aN[g][0]);
            aN[g][0] = fmaf(n4.z, w2.x, aN[g][0]);
            aN[g][0] = fmaf(n4.w, w3.x, aN[g][0]);
            aN[g][1] = fmaf(n4.x, w0.y, aN[g][1]);
            aN[g][1] = fmaf(n4.y, w1.y, aN[g][1]);
            aN[g][1] = fmaf(n4.z, w2.y, aN[g][1]);
            aN[g][1] = fmaf(n4.w, w3.y, aN[g][1]);
        }
    }

    // ---- cross-wave reduce, 2 rounds of 4 samples ----
#pragma unroll
    for (int r0 = 0; r0 < G; r0 += 4) {
        if (r0) __syncthreads();  // prior round's epi reads done
#pragma unroll
        for (int g = 0; g < 4; ++g) {
            const int gg = r0 + g;
            *(float2*)&epi[g][0][q][cb] = make_float2(aH[gg][0], aH[gg][1]);
            *(float2*)&epi[g][1][q][cb] = make_float2(aP[gg][0], aP[gg][1]);
            *(float2*)&epi[g][2][q][cb] = make_float2(aN[gg][0], aN[gg][1]);
        }
        __syncthreads();  // epi visible

        if (t < E_DIM) {  // waves 0,1 finalize; col = t
#pragma unroll
            for (int g = 0; g < 4; ++g) {
                const int gg = r0 + g;
                float hv = (epi[g][0][0][t] + epi[g][0][1][t]) + (epi[g][0][2][t] + epi[g][0][3][t]);
                float pv = (epi[g][1][0][t] + epi[g][1][1][t]) + (epi[g][1][2][t] + epi[g][1][3][t]);
                float nv = (epi[g][2][0][t] + epi[g][2][1][t]) + (epi[g][2][2][t] + epi[g][2][3][t]);
                float he = sh[gg][t], pe = sp[gg][t], ne = sn[gg][t];
                float a  = hv + re;
                float dp = a - pv;
                float dn = a - nv;
                float pos = dp * dp;
                float neg = dn * dn;
                float reg = he * he + re * re + pe * pe + ne * ne;
#pragma unroll
                for (int off = 32; off > 0; off >>= 1) {
                    pos += __shfl_down(pos, off);
                    neg += __shfl_down(neg, off);
                    reg += __shfl_down(reg, off);
                }
                if ((t & 63) == 0) {
                    wpart[0][gg][t >> 6] = pos;
                    wpart[1][gg][t >> 6] = neg;
                    wpart[2][gg][t >> 6] = reg;
                }
            }
        }
    }
    __syncthreads();  // wpart visible

    if (t < len) {  // t < G implied (len <= G)
        float P  = wpart[0][t][0] + wpart[0][t][1];
        float Nn = wpart[1][t][0] + wpart[1][t][1];
        float R  = wpart[2][t][0] + wpart[2][t][1];
        float diff = 0.5f * (P - Nn);           // pos_score - neg_score
        float z = -diff;                        // -log_sigmoid = softplus(-diff)
        float sp_v = fmaxf(z, 0.f) + log1pf(expf(-fabsf(z)));
        per_sample[s_ids[t]] = sp_v + REG_LAMBDA * 0.5f * R;
    }
}

// ---------------- final reduction -> mean (deterministic order) -------------
__global__ void __launch_bounds__(256)
kge_reduce_kernel(const float* __restrict__ per_sample, float* __restrict__ out, int M)
{
    int t = threadIdx.x;
    float s = 0.f;
    for (int i = t; i < M; i += 256) s += per_sample[i];
#pragma unroll
    for (int off = 32; off > 0; off >>= 1) s += __shfl_down(s, off);
    __shared__ float part[4];
    if ((t & 63) == 0) part[t >> 6] = s;
    __syncthreads();
    if (t == 0) out[0] = (part[0] + part[1] + part[2] + part[3]) / (float)M;
}

extern "C" void kernel_launch(void* const* d_in, const int* in_sizes, int n_in,
                              void* d_out, int out_size, void* d_ws, size_t ws_size,
                              hipStream_t stream)
{
    const int*   h_idx  = (const int*)d_in[0];
    const int*   r_idx  = (const int*)d_in[1];
    const int*   pt_idx = (const int*)d_in[2];
    const int*   nt_idx = (const int*)d_in[3];
    const float* ent    = (const float*)d_in[4];
    const float* rel    = (const float*)d_in[5];
    const float* W      = (const float*)d_in[6];
    float* out = (float*)d_out;

    int M = in_sizes[0];
    const int maxChunks = (M + G - 1) / G + N_REL;  // upper bound on padded chunks

    // workspace layout
    float* per_sample = (float*)d_ws;                  // M floats
    int*   sorted     = (int*)(per_sample + M);        // M ints
    int2*  desc       = (int2*)(sorted + M);           // maxChunks int2 (8B-aligned)
    int*   nchunks    = (int*)(desc + maxChunks);      // 1 int

    kge_sort_kernel<<<1, 1024, 0, stream>>>(r_idx, M, sorted, desc, nchunks);
    kge_chunk_kernel<<<maxChunks, 256, 0, stream>>>(sorted, desc, nchunks,
                                                    h_idx, pt_idx, nt_idx,
                                                    ent, rel, W, per_sample);
    kge_reduce_kernel<<<1, 256, 0, stream>>>(per_sample, out, M);
}